// Round 16
// baseline (208.369 us; speedup 1.0000x reference)
//
#include <hip/hip_runtime.h>
#include <cstdint>
#include <math.h>

typedef unsigned short ushort_t;
typedef unsigned int uint_t;
typedef __bf16 v8bf __attribute__((ext_vector_type(8)));
typedef float v16f __attribute__((ext_vector_type(16)));

constexpr int B_SZ = 32, NQ = 2048, NK = 2048, DH = 128;
constexpr int BK = 64;
constexpr int TILE_E = 8192;  // ushorts per 64-key frag-tile (64 keys x 128 d)
// Q prescaled by (1/sqrt(128))*log2(e); softmax = v_exp_f32(s' - M2) (2^x).
// Fixed-shift softmax (r3-15 verified): partials over disjoint keys ADD ->
// 4-way wave-parity split-K merges by pure addition.
constexpr float QSCALE = 0.12751880226116815f;
constexpr float M2 = 17.312340490667561f;

__device__ __forceinline__ float4 ld4f(const float* p) {
  return *reinterpret_cast<const float4*>(p);
}
__device__ __forceinline__ uint4 ld4u(const ushort_t* p) {
  return *reinterpret_cast<const uint4*>(p);
}

__device__ inline v8bf cvt8(const float* __restrict__ p) {
  float4 f0 = ld4f(p);
  float4 f1 = ld4f(p + 4);
  v8bf r;
  r[0] = (__bf16)f0.x; r[1] = (__bf16)f0.y; r[2] = (__bf16)f0.z; r[3] = (__bf16)f0.w;
  r[4] = (__bf16)f1.x; r[5] = (__bf16)f1.y; r[6] = (__bf16)f1.z; r[7] = (__bf16)f1.w;
  return r;
}

__device__ inline v8bf cvt8s(const float* __restrict__ p, float s) {
  float4 f0 = ld4f(p);
  float4 f1 = ld4f(p + 4);
  v8bf r;
  r[0] = (__bf16)(f0.x * s); r[1] = (__bf16)(f0.y * s);
  r[2] = (__bf16)(f0.z * s); r[3] = (__bf16)(f0.w * s);
  r[4] = (__bf16)(f1.x * s); r[5] = (__bf16)(f1.y * s);
  r[6] = (__bf16)(f1.z * s); r[7] = (__bf16)(f1.w * s);
  return r;
}

__device__ __forceinline__ uint_t pk2(float a, float b) {
  const ushort_t ua = __builtin_bit_cast(ushort_t, (__bf16)a);
  const ushort_t ub = __builtin_bit_cast(ushort_t, (__bf16)b);
  return (uint_t)ua | ((uint_t)ub << 16);
}

// ---- prep_kv: one launch builds both frag streams (r15 layouts, verified).
// Kf[b][t][kb][ks][hi][l32]*8 = bf16 K[b][t*64+kb*32+l32][(2ks+hi)*8..+7]
// Vf[b][t][ksg][hi][nb][l32]*8 = bf16 V[b][t*64+ksg*16+hi*8+j][nb*32+l32]
__global__ __launch_bounds__(256) void prep_kv(const float* __restrict__ K,
                                               const float* __restrict__ V,
                                               ushort_t* __restrict__ Kf,
                                               ushort_t* __restrict__ Vf) {
  __shared__ __align__(16) ushort_t st[64 * 128];
  const int b = blockIdx.y, tq = blockIdx.x, k0 = tq * 64, t = threadIdx.x;
  const int l32 = t & 31, g = t >> 5;
  // --- K part (register-only) ---
  {
    const float* Kb = K + ((size_t)(b * NK + k0)) * DH;
    ushort_t* out = Kf + ((size_t)(b * 32 + tq)) * TILE_E;
    for (int c = 0; c < 4; ++c) {
      const int id = g * 4 + c;  // 0..31 = kb*16 + ks*2 + hi
      const int kb = id >> 4, ks = (id >> 1) & 7, hi = id & 1;
      v8bf v = cvt8(Kb + (size_t)(kb * 32 + l32) * DH + (2 * ks + hi) * 8);
      *reinterpret_cast<v8bf*>(out + (size_t)id * 256 + l32 * 8) = v;
    }
  }
  // --- V part (swizzled LDS transpose) ---
  for (int c = 0; c < 4; ++c) {
    const int row = (t >> 4) + 16 * c;
    const int col = (t & 15) * 8;
    v8bf v = cvt8(V + ((size_t)(b * NK + k0 + row)) * DH + col);
    const int chunk = (col >> 3) ^ ((row >> 3) & 7);
    *reinterpret_cast<v8bf*>(&st[row * 128 + chunk * 8]) = v;
  }
  __syncthreads();
  {
    ushort_t* out = Vf + ((size_t)(b * 32 + tq)) * TILE_E;
    for (int c = 0; c < 4; ++c) {
      const int f = g + 8 * c;  // 0..31
      const int nb = f & 3, hi = (f >> 2) & 1, ksg = f >> 3;
      const int d = nb * 32 + l32;
      alignas(16) ushort_t tmp[8];
      for (int j = 0; j < 8; ++j) {
        const int row = ksg * 16 + hi * 8 + j;
        const int elem = (d & 7) | (((d >> 3) ^ ((row >> 3) & 7)) << 3);
        tmp[j] = st[row * 128 + elem];
      }
      *reinterpret_cast<uint4*>(out + ((ksg * 2 + hi) * 4 + nb) * 256 + l32 * 8) =
          *reinterpret_cast<const uint4*>(tmp);
    }
  }
}

// QK^T + fixed-shift softmax + in-register P-frag build; frags from GLOBAL Kf.
__device__ __forceinline__ void qk_sm(const ushort_t* kt, int l32, int hi, int k0n,
                                      int valid, const v8bf* qf, float& ls0,
                                      float& ls1, uint4& pa0, uint4& pa1,
                                      uint4& pa2, uint4& pa3) {
  const bool part = (k0n + BK > valid);
#pragma unroll
  for (int kb = 0; kb < 2; ++kb) {
    const ushort_t* base = kt + kb * 4096 + hi * 256 + l32 * 8;
    const uint4 kf0 = ld4u(base + 0 * 512);
    const uint4 kf1 = ld4u(base + 1 * 512);
    const uint4 kf2 = ld4u(base + 2 * 512);
    const uint4 kf3 = ld4u(base + 3 * 512);
    const uint4 kf4 = ld4u(base + 4 * 512);
    const uint4 kf5 = ld4u(base + 5 * 512);
    const uint4 kf6 = ld4u(base + 6 * 512);
    const uint4 kf7 = ld4u(base + 7 * 512);
    v16f sa;
#pragma unroll
    for (int r = 0; r < 16; ++r) sa[r] = 0.f;
    __builtin_amdgcn_s_setprio(1);
    sa = __builtin_amdgcn_mfma_f32_32x32x16_bf16(__builtin_bit_cast(v8bf, kf0), qf[0], sa, 0, 0, 0);
    sa = __builtin_amdgcn_mfma_f32_32x32x16_bf16(__builtin_bit_cast(v8bf, kf1), qf[1], sa, 0, 0, 0);
    sa = __builtin_amdgcn_mfma_f32_32x32x16_bf16(__builtin_bit_cast(v8bf, kf2), qf[2], sa, 0, 0, 0);
    sa = __builtin_amdgcn_mfma_f32_32x32x16_bf16(__builtin_bit_cast(v8bf, kf3), qf[3], sa, 0, 0, 0);
    sa = __builtin_amdgcn_mfma_f32_32x32x16_bf16(__builtin_bit_cast(v8bf, kf4), qf[4], sa, 0, 0, 0);
    sa = __builtin_amdgcn_mfma_f32_32x32x16_bf16(__builtin_bit_cast(v8bf, kf5), qf[5], sa, 0, 0, 0);
    sa = __builtin_amdgcn_mfma_f32_32x32x16_bf16(__builtin_bit_cast(v8bf, kf6), qf[6], sa, 0, 0, 0);
    sa = __builtin_amdgcn_mfma_f32_32x32x16_bf16(__builtin_bit_cast(v8bf, kf7), qf[7], sa, 0, 0, 0);
    __builtin_amdgcn_s_setprio(0);
    float p[16];
#pragma unroll
    for (int r = 0; r < 16; ++r) {
      const int crow = (r & 3) + 8 * (r >> 2) + 4 * hi;  // [m74/m101]
      float x = sa[r];
      if (part) x = (k0n + kb * 32 + crow < valid) ? x : -1e30f;
      float e;
      asm("v_exp_f32 %0, %1" : "=v"(e) : "v"(x - M2));
      p[r] = e;
      if (r < 8) ls0 += e; else ls1 += e;
    }
#pragma unroll
    for (int q2 = 0; q2 < 2; ++q2) {
      uint_t A0 = pk2(p[8 * q2 + 0], p[8 * q2 + 1]);
      uint_t A1 = pk2(p[8 * q2 + 2], p[8 * q2 + 3]);
      uint_t B0 = pk2(p[8 * q2 + 4], p[8 * q2 + 5]);
      uint_t B1 = pk2(p[8 * q2 + 6], p[8 * q2 + 7]);
      asm("v_permlane32_swap_b32 %0, %1" : "+v"(A0), "+v"(B0));  // r11-verified
      asm("v_permlane32_swap_b32 %0, %1" : "+v"(A1), "+v"(B1));
      uint4 fw;
      fw.x = A0; fw.y = A1; fw.z = B0; fw.w = B1;
      if (kb == 0) { if (q2 == 0) pa0 = fw; else pa1 = fw; }
      else         { if (q2 == 0) pa2 = fw; else pa3 = fw; }
    }
  }
}

// One PV quarter; V-frags from GLOBAL Vf.
__device__ __forceinline__ void pv4(const ushort_t* vt, int l32, int hi,
                                    const uint4 paf, int ksg, v16f* o) {
  const ushort_t* vb = vt + ksg * 2048 + hi * 1024 + l32 * 8;
  const uint4 vf0 = ld4u(vb + 0 * 256);
  const uint4 vf1 = ld4u(vb + 1 * 256);
  const uint4 vf2 = ld4u(vb + 2 * 256);
  const uint4 vf3 = ld4u(vb + 3 * 256);
  const v8bf pa = __builtin_bit_cast(v8bf, paf);
  __builtin_amdgcn_s_setprio(1);
  o[0] = __builtin_amdgcn_mfma_f32_32x32x16_bf16(pa, __builtin_bit_cast(v8bf, vf0), o[0], 0, 0, 0);
  o[1] = __builtin_amdgcn_mfma_f32_32x32x16_bf16(pa, __builtin_bit_cast(v8bf, vf1), o[1], 0, 0, 0);
  o[2] = __builtin_amdgcn_mfma_f32_32x32x16_bf16(pa, __builtin_bit_cast(v8bf, vf2), o[2], 0, 0, 0);
  o[3] = __builtin_amdgcn_mfma_f32_32x32x16_bf16(pa, __builtin_bit_cast(v8bf, vf3), o[3], 0, 0, 0);
  __builtin_amdgcn_s_setprio(0);
}

// ---------------- Flash attention: 4-way wave split-K + LPT backfill -----------
// grid 2048 x 256 threads. Block = (batch, 32 q-rows); ALL 4 waves cover the
// same rows, wave w processes tiles with tile%4 == w (barrier-free loop, frags
// stream from L2/L3-resident Kf/Vf). Max block duration <= 8 tiles/wave (was
// 16) and grid(2048) > resident(1024): retiring light blocks are backfilled
// from the queue -> occupancy decay (r15's 18%) is replaced by LPT smoothing.
// Fixed-shift softmax => the 4 partials merge by pure addition: 2-round LDS
// exchange (32KB, 3 barriers, end-only). LDS ~33KB -> 4 blocks/CU.
__global__ __launch_bounds__(256, 2) void attn(const float* __restrict__ Q,
                                               const ushort_t* __restrict__ Kf,
                                               const ushort_t* __restrict__ Vf,
                                               const int* __restrict__ vsl,
                                               float* __restrict__ Out) {
  __shared__ int s_ord[32];
  __shared__ float sRS[2][32];
  __shared__ __align__(16) float mO[2][4096];  // two 16KB merge buffers

  const int t = threadIdx.x;
  const int lane = t & 63, w = t >> 6;  // wave w = tile parity class
  const int hi = lane >> 5, l32 = lane & 31;

  // ---- in-kernel LPT scheduler ----
  if (t < 32) {
    const int cx = (vsl[t] + 63) >> 6;
    int rank = 0;
    for (int y = 0; y < 32; ++y) {
      const int cy = (vsl[y] + 63) >> 6;
      rank += (cy > cx) || (cy == cx && y < t);
    }
    s_ord[rank] = t;
  }
  __syncthreads();
  // 8-deep zigzag over descending-cost ranks: co-CU slots {ci+256k} get
  // balanced sums; ranks 0..1023 dispatch first (heavy), 1024+ backfill light.
  const int n = (int)blockIdx.x;
  const int ci = n & 255, cj = n >> 8;
  const int rk = cj * 256 + ((cj & 1) ? 255 - ci : ci);
  const int b = s_ord[rk >> 6];  // 64 q-tiles per batch rank-run
  const int qt = rk & 63;

  const int q0 = qt * 32;
  const int valid = vsl[b];
  const int nt = (valid + BK - 1) / BK;
  const int myNt = (nt > w) ? ((nt - w + 3) >> 2) : 0;  // tiles ≡ w (mod 4)

  // Q regs (prescaled): B-frag ks: lane holds Q[q=l32][d=ks*16+hi*8+j]
  v8bf qf[8];
  {
    const float* qp = Q + ((size_t)(b * NQ + q0 + l32)) * DH + hi * 8;
#pragma unroll
    for (int ks = 0; ks < 8; ++ks) qf[ks] = cvt8s(qp + ks * 16, QSCALE);
  }

  v16f o[4];
#pragma unroll
  for (int nb = 0; nb < 4; ++nb)
#pragma unroll
    for (int r = 0; r < 16; ++r) o[nb][r] = 0.f;
  float ls0 = 0.f, ls1 = 0.f;

  const ushort_t* Kb = Kf + (size_t)b * 32 * TILE_E;
  const ushort_t* Vb = Vf + (size_t)b * 32 * TILE_E;

  for (int i = 0; i < myNt; ++i) {
    const int tile = 4 * i + w;
    const ushort_t* kt = Kb + (size_t)tile * TILE_E;
    const ushort_t* vt = Vb + (size_t)tile * TILE_E;
    uint4 pa0, pa1, pa2, pa3;
    qk_sm(kt, l32, hi, tile * BK, valid, qf, ls0, ls1, pa0, pa1, pa2, pa3);
    pv4(vt, l32, hi, pa0, 0, o);
    pv4(vt, l32, hi, pa1, 1, o);
    pv4(vt, l32, hi, pa2, 2, o);
    pv4(vt, l32, hi, pa3, 3, o);
  }

  // ---- merge 4 parities (pure adds): waves {1,3} -> {0,2}, then 2 -> 0 ----
  const float lsw = ls0 + ls1;
  float rsw = lsw + __shfl_xor(lsw, 32);  // row-sum for q-row l32, this parity
  if (w == 1 || w == 3) {
    const int s = w >> 1;
#pragma unroll
    for (int nb = 0; nb < 4; ++nb)
#pragma unroll
      for (int r = 0; r < 16; ++r) mO[s][(nb * 16 + r) * 64 + lane] = o[nb][r];
    if (hi == 0) sRS[s][l32] = rsw;
  }
  __syncthreads();
  if (w == 0 || w == 2) {
    const int s = w >> 1;
#pragma unroll
    for (int nb = 0; nb < 4; ++nb)
#pragma unroll
      for (int r = 0; r < 16; ++r) o[nb][r] += mO[s][(nb * 16 + r) * 64 + lane];
    rsw += sRS[s][l32];
  }
  __syncthreads();
  if (w == 2) {
#pragma unroll
    for (int nb = 0; nb < 4; ++nb)
#pragma unroll
      for (int r = 0; r < 16; ++r) mO[0][(nb * 16 + r) * 64 + lane] = o[nb][r];
    if (hi == 0) sRS[0][l32] = rsw;
  }
  __syncthreads();
  if (w == 0) {
#pragma unroll
    for (int nb = 0; nb < 4; ++nb)
#pragma unroll
      for (int r = 0; r < 16; ++r) o[nb][r] += mO[0][(nb * 16 + r) * 64 + lane];
    const float rs = rsw + sRS[0][l32];
    const float inv_own = 1.0f / rs;
#pragma unroll
    for (int r = 0; r < 16; ++r) {
      const int crow = (r & 3) + 8 * (r >> 2) + 4 * hi;
      const float inv = __shfl(inv_own, crow);
      float* op = Out + ((size_t)(b * NQ + q0 + crow)) * DH + l32;
#pragma unroll
      for (int nb = 0; nb < 4; ++nb) op[nb * 32] = o[nb][r] * inv;
    }
  }
}

extern "C" void kernel_launch(void* const* d_in, const int* in_sizes, int n_in,
                              void* d_out, int out_size, void* d_ws, size_t ws_size,
                              hipStream_t stream) {
  const float* Q = (const float*)d_in[0];
  const float* K = (const float*)d_in[1];
  const float* V = (const float*)d_in[2];
  const int* vsl = (const int*)d_in[3];
  float* Out = (float*)d_out;

  // ws: Kf 16.78 MB + Vf 16.78 MB
  ushort_t* Kf = (ushort_t*)d_ws;
  ushort_t* Vf = Kf + (size_t)B_SZ * 32 * TILE_E;

  prep_kv<<<dim3(NK / 64, B_SZ), dim3(256), 0, stream>>>(K, V, Kf, Vf);
  attn<<<dim3(2048), dim3(256), 0, stream>>>(Q, Kf, Vf, vsl, Out);
}

// Round 17
// 196.072 us; speedup vs baseline: 1.0627x; 1.0627x over previous
//
#include <hip/hip_runtime.h>
#include <cstdint>
#include <math.h>

typedef unsigned short ushort_t;
typedef unsigned int uint_t;
typedef __bf16 v8bf __attribute__((ext_vector_type(8)));
typedef float v16f __attribute__((ext_vector_type(16)));

constexpr int B_SZ = 32, NQ = 2048, NK = 2048, DH = 128;
constexpr int BK = 64;
constexpr int TILE_E = 8192;  // ushorts per 64-key frag-tile (64 keys x 128 d)
// Q prescaled by (1/sqrt(128))*log2(e); softmax = v_exp_f32(s' - M2) (2^x).
// Fixed-shift softmax (r3-16 verified): partials over disjoint keys ADD ->
// wave-parity split-K merges by pure addition.
constexpr float QSCALE = 0.12751880226116815f;
constexpr float M2 = 17.312340490667561f;

__device__ __forceinline__ float4 ld4f(const float* p) {
  return *reinterpret_cast<const float4*>(p);
}
__device__ __forceinline__ uint4 ld4u(const ushort_t* p) {
  return *reinterpret_cast<const uint4*>(p);
}

__device__ inline v8bf cvt8(const float* __restrict__ p) {
  float4 f0 = ld4f(p);
  float4 f1 = ld4f(p + 4);
  v8bf r;
  r[0] = (__bf16)f0.x; r[1] = (__bf16)f0.y; r[2] = (__bf16)f0.z; r[3] = (__bf16)f0.w;
  r[4] = (__bf16)f1.x; r[5] = (__bf16)f1.y; r[6] = (__bf16)f1.z; r[7] = (__bf16)f1.w;
  return r;
}

__device__ inline v8bf cvt8s(const float* __restrict__ p, float s) {
  float4 f0 = ld4f(p);
  float4 f1 = ld4f(p + 4);
  v8bf r;
  r[0] = (__bf16)(f0.x * s); r[1] = (__bf16)(f0.y * s);
  r[2] = (__bf16)(f0.z * s); r[3] = (__bf16)(f0.w * s);
  r[4] = (__bf16)(f1.x * s); r[5] = (__bf16)(f1.y * s);
  r[6] = (__bf16)(f1.z * s); r[7] = (__bf16)(f1.w * s);
  return r;
}

__device__ __forceinline__ uint_t pk2(float a, float b) {
  const ushort_t ua = __builtin_bit_cast(ushort_t, (__bf16)a);
  const ushort_t ub = __builtin_bit_cast(ushort_t, (__bf16)b);
  return (uint_t)ua | ((uint_t)ub << 16);
}

// ---- prep_kv (r16-verified): one launch builds both frag streams.
// Kf[b][t][kb][ks][hi][l32]*8 = bf16 K[b][t*64+kb*32+l32][(2ks+hi)*8..+7]
// Vf[b][t][ksg][hi][nb][l32]*8 = bf16 V[b][t*64+ksg*16+hi*8+j][nb*32+l32]
__global__ __launch_bounds__(256) void prep_kv(const float* __restrict__ K,
                                               const float* __restrict__ V,
                                               ushort_t* __restrict__ Kf,
                                               ushort_t* __restrict__ Vf) {
  __shared__ __align__(16) ushort_t st[64 * 128];
  const int b = blockIdx.y, tq = blockIdx.x, k0 = tq * 64, t = threadIdx.x;
  const int l32 = t & 31, g = t >> 5;
  // --- K part (register-only) ---
  {
    const float* Kb = K + ((size_t)(b * NK + k0)) * DH;
    ushort_t* out = Kf + ((size_t)(b * 32 + tq)) * TILE_E;
    for (int c = 0; c < 4; ++c) {
      const int id = g * 4 + c;  // 0..31 = kb*16 + ks*2 + hi
      const int kb = id >> 4, ks = (id >> 1) & 7, hi = id & 1;
      v8bf v = cvt8(Kb + (size_t)(kb * 32 + l32) * DH + (2 * ks + hi) * 8);
      *reinterpret_cast<v8bf*>(out + (size_t)id * 256 + l32 * 8) = v;
    }
  }
  // --- V part (swizzled LDS transpose) ---
  for (int c = 0; c < 4; ++c) {
    const int row = (t >> 4) + 16 * c;
    const int col = (t & 15) * 8;
    v8bf v = cvt8(V + ((size_t)(b * NK + k0 + row)) * DH + col);
    const int chunk = (col >> 3) ^ ((row >> 3) & 7);
    *reinterpret_cast<v8bf*>(&st[row * 128 + chunk * 8]) = v;
  }
  __syncthreads();
  {
    ushort_t* out = Vf + ((size_t)(b * 32 + tq)) * TILE_E;
    for (int c = 0; c < 4; ++c) {
      const int f = g + 8 * c;  // 0..31
      const int nb = f & 3, hi = (f >> 2) & 1, ksg = f >> 3;
      const int d = nb * 32 + l32;
      alignas(16) ushort_t tmp[8];
      for (int j = 0; j < 8; ++j) {
        const int row = ksg * 16 + hi * 8 + j;
        const int elem = (d & 7) | (((d >> 3) ^ ((row >> 3) & 7)) << 3);
        tmp[j] = st[row * 128 + elem];
      }
      *reinterpret_cast<uint4*>(out + ((ksg * 2 + hi) * 4 + nb) * 256 + l32 * 8) =
          *reinterpret_cast<const uint4*>(tmp);
    }
  }
}

// QK^T + fixed-shift softmax + in-register P-frag build; frags from GLOBAL Kf.
__device__ __forceinline__ void qk_sm(const ushort_t* kt, int l32, int hi, int k0n,
                                      int valid, const v8bf* qf, float& ls0,
                                      float& ls1, uint4& pa0, uint4& pa1,
                                      uint4& pa2, uint4& pa3) {
  const bool part = (k0n + BK > valid);
#pragma unroll
  for (int kb = 0; kb < 2; ++kb) {
    const ushort_t* base = kt + kb * 4096 + hi * 256 + l32 * 8;
    const uint4 kf0 = ld4u(base + 0 * 512);
    const uint4 kf1 = ld4u(base + 1 * 512);
    const uint4 kf2 = ld4u(base + 2 * 512);
    const uint4 kf3 = ld4u(base + 3 * 512);
    const uint4 kf4 = ld4u(base + 4 * 512);
    const uint4 kf5 = ld4u(base + 5 * 512);
    const uint4 kf6 = ld4u(base + 6 * 512);
    const uint4 kf7 = ld4u(base + 7 * 512);
    v16f sa;
#pragma unroll
    for (int r = 0; r < 16; ++r) sa[r] = 0.f;
    __builtin_amdgcn_s_setprio(1);
    sa = __builtin_amdgcn_mfma_f32_32x32x16_bf16(__builtin_bit_cast(v8bf, kf0), qf[0], sa, 0, 0, 0);
    sa = __builtin_amdgcn_mfma_f32_32x32x16_bf16(__builtin_bit_cast(v8bf, kf1), qf[1], sa, 0, 0, 0);
    sa = __builtin_amdgcn_mfma_f32_32x32x16_bf16(__builtin_bit_cast(v8bf, kf2), qf[2], sa, 0, 0, 0);
    sa = __builtin_amdgcn_mfma_f32_32x32x16_bf16(__builtin_bit_cast(v8bf, kf3), qf[3], sa, 0, 0, 0);
    sa = __builtin_amdgcn_mfma_f32_32x32x16_bf16(__builtin_bit_cast(v8bf, kf4), qf[4], sa, 0, 0, 0);
    sa = __builtin_amdgcn_mfma_f32_32x32x16_bf16(__builtin_bit_cast(v8bf, kf5), qf[5], sa, 0, 0, 0);
    sa = __builtin_amdgcn_mfma_f32_32x32x16_bf16(__builtin_bit_cast(v8bf, kf6), qf[6], sa, 0, 0, 0);
    sa = __builtin_amdgcn_mfma_f32_32x32x16_bf16(__builtin_bit_cast(v8bf, kf7), qf[7], sa, 0, 0, 0);
    __builtin_amdgcn_s_setprio(0);
    float p[16];
#pragma unroll
    for (int r = 0; r < 16; ++r) {
      const int crow = (r & 3) + 8 * (r >> 2) + 4 * hi;  // [m74/m101]
      float x = sa[r];
      if (part) x = (k0n + kb * 32 + crow < valid) ? x : -1e30f;
      float e;
      asm("v_exp_f32 %0, %1" : "=v"(e) : "v"(x - M2));
      p[r] = e;
      if (r < 8) ls0 += e; else ls1 += e;
    }
#pragma unroll
    for (int q2 = 0; q2 < 2; ++q2) {
      uint_t A0 = pk2(p[8 * q2 + 0], p[8 * q2 + 1]);
      uint_t A1 = pk2(p[8 * q2 + 2], p[8 * q2 + 3]);
      uint_t B0 = pk2(p[8 * q2 + 4], p[8 * q2 + 5]);
      uint_t B1 = pk2(p[8 * q2 + 6], p[8 * q2 + 7]);
      asm("v_permlane32_swap_b32 %0, %1" : "+v"(A0), "+v"(B0));  // r11-verified
      asm("v_permlane32_swap_b32 %0, %1" : "+v"(A1), "+v"(B1));
      uint4 fw;
      fw.x = A0; fw.y = A1; fw.z = B0; fw.w = B1;
      if (kb == 0) { if (q2 == 0) pa0 = fw; else pa1 = fw; }
      else         { if (q2 == 0) pa2 = fw; else pa3 = fw; }
    }
  }
}

// One PV quarter; V-frags from GLOBAL Vf.
__device__ __forceinline__ void pv4(const ushort_t* vt, int l32, int hi,
                                    const uint4 paf, int ksg, v16f* o) {
  const ushort_t* vb = vt + ksg * 2048 + hi * 1024 + l32 * 8;
  const uint4 vf0 = ld4u(vb + 0 * 256);
  const uint4 vf1 = ld4u(vb + 1 * 256);
  const uint4 vf2 = ld4u(vb + 2 * 256);
  const uint4 vf3 = ld4u(vb + 3 * 256);
  const v8bf pa = __builtin_bit_cast(v8bf, paf);
  __builtin_amdgcn_s_setprio(1);
  o[0] = __builtin_amdgcn_mfma_f32_32x32x16_bf16(pa, __builtin_bit_cast(v8bf, vf0), o[0], 0, 0, 0);
  o[1] = __builtin_amdgcn_mfma_f32_32x32x16_bf16(pa, __builtin_bit_cast(v8bf, vf1), o[1], 0, 0, 0);
  o[2] = __builtin_amdgcn_mfma_f32_32x32x16_bf16(pa, __builtin_bit_cast(v8bf, vf2), o[2], 0, 0, 0);
  o[3] = __builtin_amdgcn_mfma_f32_32x32x16_bf16(pa, __builtin_bit_cast(v8bf, vf3), o[3], 0, 0, 0);
  __builtin_amdgcn_s_setprio(0);
}

// ---------------- Flash attention (r15-verified, 82us): frag-streaming --------
// grid 1024 x 256 threads. Block = (batch, 64 q-rows): waves {0,1} = q-row
// halves x EVEN tiles, waves {2,3} = same rows x ODD tiles. Loop has ZERO
// LDS ops and ZERO barriers; groups couple only at the final additive merge
// (fixed-shift softmax). 4 blocks/CU (LDS 33KB). r16 showed finer split (4-way,
// 2048 blocks) loses to per-block fixed costs — this granularity is the optimum.
__global__ __launch_bounds__(256, 2) void attn(const float* __restrict__ Q,
                                               const ushort_t* __restrict__ Kf,
                                               const ushort_t* __restrict__ Vf,
                                               const int* __restrict__ vsl,
                                               float* __restrict__ Out) {
  __shared__ int s_ord[32];
  __shared__ float mO[2][4096];  // odd-parity O partials: [wq][(nb*16+r)*64+lane]
  __shared__ float sRS[2][32];   // odd-parity row-sums

  const int t = threadIdx.x;
  const int lane = t & 63, w = t >> 6;
  const int wq = w & 1, pr = w >> 1;  // q-half, tile parity
  const int hi = lane >> 5, l32 = lane & 31;

  // ---- in-kernel LPT scheduler ----
  if (t < 32) {
    const int cx = (vsl[t] + 63) >> 6;
    int rank = 0;
    for (int y = 0; y < 32; ++y) {
      const int cy = (vsl[y] + 63) >> 6;
      rank += (cy > cx) || (cy == cx && y < t);
    }
    s_ord[rank] = t;
  }
  __syncthreads();
  const int n = (int)blockIdx.x;
  const int ci = n & 255, cj = n >> 8;
  const int rk = (cj == 0) ? ci : (cj == 1) ? 511 - ci : (cj == 2) ? 512 + ci : 1023 - ci;
  const int b = s_ord[rk >> 5];  // 4-deep zigzag over desc-cost ranks (r7-proven)
  const int qt = rk & 31;

  const int q0 = qt * 64;
  const int valid = vsl[b];
  const int nt = (valid + BK - 1) / BK;
  const int myNt = (nt + 1 - pr) >> 1;  // #tiles with parity pr

  // Q regs (prescaled): B-frag ks: lane holds Q[q=l32][d=ks*16+hi*8+j]
  v8bf qf[8];
  {
    const float* qp = Q + ((size_t)(b * NQ + q0 + wq * 32 + l32)) * DH + hi * 8;
#pragma unroll
    for (int ks = 0; ks < 8; ++ks) qf[ks] = cvt8s(qp + ks * 16, QSCALE);
  }

  v16f o[4];
#pragma unroll
  for (int nb = 0; nb < 4; ++nb)
#pragma unroll
    for (int r = 0; r < 16; ++r) o[nb][r] = 0.f;
  float ls0 = 0.f, ls1 = 0.f;

  const ushort_t* Kb = Kf + (size_t)b * 32 * TILE_E;
  const ushort_t* Vb = Vf + (size_t)b * 32 * TILE_E;

  for (int i = 0; i < myNt; ++i) {
    const int tile = 2 * i + pr;
    const ushort_t* kt = Kb + (size_t)tile * TILE_E;
    const ushort_t* vt = Vb + (size_t)tile * TILE_E;
    uint4 pa0, pa1, pa2, pa3;
    qk_sm(kt, l32, hi, tile * BK, valid, qf, ls0, ls1, pa0, pa1, pa2, pa3);
    pv4(vt, l32, hi, pa0, 0, o);
    pv4(vt, l32, hi, pa1, 1, o);
    pv4(vt, l32, hi, pa2, 2, o);
    pv4(vt, l32, hi, pa3, 3, o);
  }

  // ---- merge parities (pure adds; fixed-shift softmax) + normalize + store ----
  const float lsw = ls0 + ls1;
  const float rsw = lsw + __shfl_xor(lsw, 32);  // row-sum for q-row l32, this parity
  if (pr == 1) {
#pragma unroll
    for (int nb = 0; nb < 4; ++nb)
#pragma unroll
      for (int r = 0; r < 16; ++r)
        mO[wq][(nb * 16 + r) * 64 + lane] = o[nb][r];  // lane-consecutive: no conflicts
    if (hi == 0) sRS[wq][l32] = rsw;
  }
  __syncthreads();
  if (pr == 0) {
    const float rs = rsw + sRS[wq][l32];
#pragma unroll
    for (int nb = 0; nb < 4; ++nb)
#pragma unroll
      for (int r = 0; r < 16; ++r) o[nb][r] += mO[wq][(nb * 16 + r) * 64 + lane];
    const float inv_own = 1.0f / rs;
#pragma unroll
    for (int r = 0; r < 16; ++r) {
      const int crow = (r & 3) + 8 * (r >> 2) + 4 * hi;
      const float inv = __shfl(inv_own, crow);
      float* op = Out + ((size_t)(b * NQ + q0 + wq * 32 + crow)) * DH + l32;
#pragma unroll
      for (int nb = 0; nb < 4; ++nb) op[nb * 32] = o[nb][r] * inv;
    }
  }
}

extern "C" void kernel_launch(void* const* d_in, const int* in_sizes, int n_in,
                              void* d_out, int out_size, void* d_ws, size_t ws_size,
                              hipStream_t stream) {
  const float* Q = (const float*)d_in[0];
  const float* K = (const float*)d_in[1];
  const float* V = (const float*)d_in[2];
  const int* vsl = (const int*)d_in[3];
  float* Out = (float*)d_out;

  // ws: Kf 16.78 MB + Vf 16.78 MB
  ushort_t* Kf = (ushort_t*)d_ws;
  ushort_t* Vf = Kf + (size_t)B_SZ * 32 * TILE_E;

  prep_kv<<<dim3(NK / 64, B_SZ), dim3(256), 0, stream>>>(K, V, Kf, Vf);
  attn<<<dim3(1024), dim3(256), 0, stream>>>(Q, Kf, Vf, vsl, Out);
}

// Round 18
// 193.396 us; speedup vs baseline: 1.0774x; 1.0138x over previous
//
#include <hip/hip_runtime.h>
#include <cstdint>
#include <math.h>

typedef unsigned short ushort_t;
typedef unsigned int uint_t;
typedef __bf16 v8bf __attribute__((ext_vector_type(8)));
typedef float v16f __attribute__((ext_vector_type(16)));

constexpr int B_SZ = 32, NQ = 2048, NK = 2048, DH = 128;
constexpr int BK = 64;
constexpr int TILE_E = 8192;  // ushorts per 64-key frag-tile (64 keys x 128 d)
// Q prescaled by (1/sqrt(128))*log2(e); softmax = v_exp_f32(s' - M2) (2^x).
// Fixed-shift softmax (r3-17 verified): partials over disjoint keys ADD ->
// wave-parity split-K merges by pure addition.
constexpr float QSCALE = 0.12751880226116815f;
constexpr float M2 = 17.312340490667561f;

__device__ __forceinline__ float4 ld4f(const float* p) {
  return *reinterpret_cast<const float4*>(p);
}
__device__ __forceinline__ uint4 ld4u(const ushort_t* p) {
  return *reinterpret_cast<const uint4*>(p);
}

__device__ inline v8bf cvt8(const float* __restrict__ p) {
  float4 f0 = ld4f(p);
  float4 f1 = ld4f(p + 4);
  v8bf r;
  r[0] = (__bf16)f0.x; r[1] = (__bf16)f0.y; r[2] = (__bf16)f0.z; r[3] = (__bf16)f0.w;
  r[4] = (__bf16)f1.x; r[5] = (__bf16)f1.y; r[6] = (__bf16)f1.z; r[7] = (__bf16)f1.w;
  return r;
}

__device__ inline v8bf cvt8s(const float* __restrict__ p, float s) {
  float4 f0 = ld4f(p);
  float4 f1 = ld4f(p + 4);
  v8bf r;
  r[0] = (__bf16)(f0.x * s); r[1] = (__bf16)(f0.y * s);
  r[2] = (__bf16)(f0.z * s); r[3] = (__bf16)(f0.w * s);
  r[4] = (__bf16)(f1.x * s); r[5] = (__bf16)(f1.y * s);
  r[6] = (__bf16)(f1.z * s); r[7] = (__bf16)(f1.w * s);
  return r;
}

__device__ __forceinline__ uint_t pk2(float a, float b) {
  const ushort_t ua = __builtin_bit_cast(ushort_t, (__bf16)a);
  const ushort_t ub = __builtin_bit_cast(ushort_t, (__bf16)b);
  return (uint_t)ua | ((uint_t)ub << 16);
}

// ---- prep_kv (r16/r17-verified): one launch builds both frag streams.
// Kf[b][t][kb][ks][hi][l32]*8 = bf16 K[b][t*64+kb*32+l32][(2ks+hi)*8..+7]
// Vf[b][t][ksg][hi][nb][l32]*8 = bf16 V[b][t*64+ksg*16+hi*8+j][nb*32+l32]
__global__ __launch_bounds__(256) void prep_kv(const float* __restrict__ K,
                                               const float* __restrict__ V,
                                               ushort_t* __restrict__ Kf,
                                               ushort_t* __restrict__ Vf) {
  __shared__ __align__(16) ushort_t st[64 * 128];
  const int b = blockIdx.y, tq = blockIdx.x, k0 = tq * 64, t = threadIdx.x;
  const int l32 = t & 31, g = t >> 5;
  {
    const float* Kb = K + ((size_t)(b * NK + k0)) * DH;
    ushort_t* out = Kf + ((size_t)(b * 32 + tq)) * TILE_E;
    for (int c = 0; c < 4; ++c) {
      const int id = g * 4 + c;  // 0..31 = kb*16 + ks*2 + hi
      const int kb = id >> 4, ks = (id >> 1) & 7, hi = id & 1;
      v8bf v = cvt8(Kb + (size_t)(kb * 32 + l32) * DH + (2 * ks + hi) * 8);
      *reinterpret_cast<v8bf*>(out + (size_t)id * 256 + l32 * 8) = v;
    }
  }
  for (int c = 0; c < 4; ++c) {
    const int row = (t >> 4) + 16 * c;
    const int col = (t & 15) * 8;
    v8bf v = cvt8(V + ((size_t)(b * NK + k0 + row)) * DH + col);
    const int chunk = (col >> 3) ^ ((row >> 3) & 7);
    *reinterpret_cast<v8bf*>(&st[row * 128 + chunk * 8]) = v;
  }
  __syncthreads();
  {
    ushort_t* out = Vf + ((size_t)(b * 32 + tq)) * TILE_E;
    for (int c = 0; c < 4; ++c) {
      const int f = g + 8 * c;  // 0..31
      const int nb = f & 3, hi = (f >> 2) & 1, ksg = f >> 3;
      const int d = nb * 32 + l32;
      alignas(16) ushort_t tmp[8];
      for (int j = 0; j < 8; ++j) {
        const int row = ksg * 16 + hi * 8 + j;
        const int elem = (d & 7) | (((d >> 3) ^ ((row >> 3) & 7)) << 3);
        tmp[j] = st[row * 128 + elem];
      }
      *reinterpret_cast<uint4*>(out + ((ksg * 2 + hi) * 4 + nb) * 256 + l32 * 8) =
          *reinterpret_cast<const uint4*>(tmp);
    }
  }
}

// 8-step QK MFMA chain from 8 preloaded K-frag registers.
__device__ __forceinline__ v16f mfma8(uint4 f0, uint4 f1, uint4 f2, uint4 f3,
                                      uint4 f4, uint4 f5, uint4 f6, uint4 f7,
                                      const v8bf* qf) {
  v16f sa;
#pragma unroll
  for (int r = 0; r < 16; ++r) sa[r] = 0.f;
  __builtin_amdgcn_s_setprio(1);
  sa = __builtin_amdgcn_mfma_f32_32x32x16_bf16(__builtin_bit_cast(v8bf, f0), qf[0], sa, 0, 0, 0);
  sa = __builtin_amdgcn_mfma_f32_32x32x16_bf16(__builtin_bit_cast(v8bf, f1), qf[1], sa, 0, 0, 0);
  sa = __builtin_amdgcn_mfma_f32_32x32x16_bf16(__builtin_bit_cast(v8bf, f2), qf[2], sa, 0, 0, 0);
  sa = __builtin_amdgcn_mfma_f32_32x32x16_bf16(__builtin_bit_cast(v8bf, f3), qf[3], sa, 0, 0, 0);
  sa = __builtin_amdgcn_mfma_f32_32x32x16_bf16(__builtin_bit_cast(v8bf, f4), qf[4], sa, 0, 0, 0);
  sa = __builtin_amdgcn_mfma_f32_32x32x16_bf16(__builtin_bit_cast(v8bf, f5), qf[5], sa, 0, 0, 0);
  sa = __builtin_amdgcn_mfma_f32_32x32x16_bf16(__builtin_bit_cast(v8bf, f6), qf[6], sa, 0, 0, 0);
  sa = __builtin_amdgcn_mfma_f32_32x32x16_bf16(__builtin_bit_cast(v8bf, f7), qf[7], sa, 0, 0, 0);
  __builtin_amdgcn_s_setprio(0);
  return sa;
}

// mask + fixed-shift softmax + pack one kb-half into two PV A-frags.
// kbase = k0n + kb*32. Layouts r11-verified (crow map m74/m101; swap(A,B)).
__device__ __forceinline__ void smpack(const v16f& sa, int kbase, int valid,
                                       bool part, int hi, float& ls0, float& ls1,
                                       uint4& paX, uint4& paY) {
  float p[16];
#pragma unroll
  for (int r = 0; r < 16; ++r) {
    const int crow = (r & 3) + 8 * (r >> 2) + 4 * hi;
    float x = sa[r];
    if (part) x = (kbase + crow < valid) ? x : -1e30f;
    float e;
    asm("v_exp_f32 %0, %1" : "=v"(e) : "v"(x - M2));
    p[r] = e;
    if (r < 8) ls0 += e; else ls1 += e;
  }
  uint_t A0 = pk2(p[0], p[1]), A1 = pk2(p[2], p[3]);
  uint_t B0 = pk2(p[4], p[5]), B1 = pk2(p[6], p[7]);
  asm("v_permlane32_swap_b32 %0, %1" : "+v"(A0), "+v"(B0));
  asm("v_permlane32_swap_b32 %0, %1" : "+v"(A1), "+v"(B1));
  paX.x = A0; paX.y = A1; paX.z = B0; paX.w = B1;
  uint_t C0 = pk2(p[8], p[9]), C1 = pk2(p[10], p[11]);
  uint_t D0 = pk2(p[12], p[13]), D1 = pk2(p[14], p[15]);
  asm("v_permlane32_swap_b32 %0, %1" : "+v"(C0), "+v"(D0));
  asm("v_permlane32_swap_b32 %0, %1" : "+v"(C1), "+v"(D1));
  paY.x = C0; paY.y = C1; paY.z = D0; paY.w = D1;
}

// One PV quarter; V-frags from GLOBAL Vf.
__device__ __forceinline__ void pv4(const ushort_t* vt, int l32, int hi,
                                    const uint4 paf, int ksg, v16f* o) {
  const ushort_t* vb = vt + ksg * 2048 + hi * 1024 + l32 * 8;
  const uint4 vf0 = ld4u(vb + 0 * 256);
  const uint4 vf1 = ld4u(vb + 1 * 256);
  const uint4 vf2 = ld4u(vb + 2 * 256);
  const uint4 vf3 = ld4u(vb + 3 * 256);
  const v8bf pa = __builtin_bit_cast(v8bf, paf);
  __builtin_amdgcn_s_setprio(1);
  o[0] = __builtin_amdgcn_mfma_f32_32x32x16_bf16(pa, __builtin_bit_cast(v8bf, vf0), o[0], 0, 0, 0);
  o[1] = __builtin_amdgcn_mfma_f32_32x32x16_bf16(pa, __builtin_bit_cast(v8bf, vf1), o[1], 0, 0, 0);
  o[2] = __builtin_amdgcn_mfma_f32_32x32x16_bf16(pa, __builtin_bit_cast(v8bf, vf2), o[2], 0, 0, 0);
  o[3] = __builtin_amdgcn_mfma_f32_32x32x16_bf16(pa, __builtin_bit_cast(v8bf, vf3), o[3], 0, 0, 0);
  __builtin_amdgcn_s_setprio(0);
}

// issue 8 K-frag loads into named uint4s
#define LDK8(A0, A1, A2, A3, A4, A5, A6, A7, KT, KB)            \
  do {                                                          \
    const ushort_t* b_ = (KT) + (KB)*4096 + hi * 256 + l32 * 8; \
    A0 = ld4u(b_ + 0 * 512);                                    \
    A1 = ld4u(b_ + 1 * 512);                                    \
    A2 = ld4u(b_ + 2 * 512);                                    \
    A3 = ld4u(b_ + 3 * 512);                                    \
    A4 = ld4u(b_ + 4 * 512);                                    \
    A5 = ld4u(b_ + 5 * 512);                                    \
    A6 = ld4u(b_ + 6 * 512);                                    \
    A7 = ld4u(b_ + 7 * 512);                                    \
  } while (0)

// tile body: USE set = preloaded kb0 frags of tile(2i+pr); PRE set = loads
// kb0 frags of tile(2(i+1)+pr) issued BEFORE PV so their L2 latency hides
// under sm1 + 16 PV MFMAs (~700 cyc). kb1 loads issue right after kb0's
// MFMAs and hide under sm0 (~250 cyc VALU).
#define TILE_BODY(U0, U1, U2, U3, U4, U5, U6, U7,                           \
                  P0, P1, P2, P3, P4, P5, P6, P7, I)                        \
  do {                                                                      \
    const int tile_ = 2 * (I) + pr;                                         \
    const ushort_t* kt_ = Kb + (size_t)tile_ * TILE_E;                      \
    const ushort_t* vt_ = Vb + (size_t)tile_ * TILE_E;                      \
    const int k0n_ = tile_ * BK;                                            \
    const bool part_ = (k0n_ + BK > valid);                                 \
    v16f sa0_ = mfma8(U0, U1, U2, U3, U4, U5, U6, U7, qf);                  \
    uint4 t0_, t1_, t2_, t3_, t4_, t5_, t6_, t7_;                           \
    LDK8(t0_, t1_, t2_, t3_, t4_, t5_, t6_, t7_, kt_, 1);                   \
    uint4 pa0_, pa1_, pa2_, pa3_;                                           \
    smpack(sa0_, k0n_, valid, part_, hi, ls0, ls1, pa0_, pa1_);             \
    v16f sa1_ = mfma8(t0_, t1_, t2_, t3_, t4_, t5_, t6_, t7_, qf);          \
    {                                                                       \
      int nt_ = 2 * ((I) + 1) + pr;                                         \
      nt_ = nt_ <= 31 ? nt_ : 31; /* clamp: Kf always has 32 tiles */       \
      const ushort_t* nk_ = Kb + (size_t)nt_ * TILE_E;                      \
      LDK8(P0, P1, P2, P3, P4, P5, P6, P7, nk_, 0);                         \
    }                                                                       \
    smpack(sa1_, k0n_ + 32, valid, part_, hi, ls0, ls1, pa2_, pa3_);        \
    pv4(vt_, l32, hi, pa0_, 0, o);                                          \
    pv4(vt_, l32, hi, pa1_, 1, o);                                          \
    pv4(vt_, l32, hi, pa2_, 2, o);                                          \
    pv4(vt_, l32, hi, pa3_, 3, o);                                          \
  } while (0)

// ---------------- Flash attention: frag-streaming + reg ping-pong pipeline -----
// r15/r17 structure (grid 1024 x 256, waves = q-half x tile-parity, barrier-free
// loop, end-only additive merge) + software pipeline: next-tile kb0 K-frags
// prefetched into the alternate named-register set across the PV span.
__global__ __launch_bounds__(256, 2) void attn(const float* __restrict__ Q,
                                               const ushort_t* __restrict__ Kf,
                                               const ushort_t* __restrict__ Vf,
                                               const int* __restrict__ vsl,
                                               float* __restrict__ Out) {
  __shared__ int s_ord[32];
  __shared__ float mO[2][4096];  // odd-parity O partials
  __shared__ float sRS[2][32];   // odd-parity row-sums

  const int t = threadIdx.x;
  const int lane = t & 63, w = t >> 6;
  const int wq = w & 1, pr = w >> 1;  // q-half, tile parity
  const int hi = lane >> 5, l32 = lane & 31;

  // ---- in-kernel LPT scheduler ----
  if (t < 32) {
    const int cx = (vsl[t] + 63) >> 6;
    int rank = 0;
    for (int y = 0; y < 32; ++y) {
      const int cy = (vsl[y] + 63) >> 6;
      rank += (cy > cx) || (cy == cx && y < t);
    }
    s_ord[rank] = t;
  }
  __syncthreads();
  const int n = (int)blockIdx.x;
  const int ci = n & 255, cj = n >> 8;
  const int rk = (cj == 0) ? ci : (cj == 1) ? 511 - ci : (cj == 2) ? 512 + ci : 1023 - ci;
  const int b = s_ord[rk >> 5];  // 4-deep zigzag over desc-cost ranks
  const int qt = rk & 31;

  const int q0 = qt * 64;
  const int valid = vsl[b];
  const int nt = (valid + BK - 1) / BK;
  const int myNt = (nt + 1 - pr) >> 1;  // #tiles with parity pr

  // Q regs (prescaled): B-frag ks: lane holds Q[q=l32][d=ks*16+hi*8+j]
  v8bf qf[8];
  {
    const float* qp = Q + ((size_t)(b * NQ + q0 + wq * 32 + l32)) * DH + hi * 8;
#pragma unroll
    for (int ks = 0; ks < 8; ++ks) qf[ks] = cvt8s(qp + ks * 16, QSCALE);
  }

  v16f o[4];
#pragma unroll
  for (int nb = 0; nb < 4; ++nb)
#pragma unroll
    for (int r = 0; r < 16; ++r) o[nb][r] = 0.f;
  float ls0 = 0.f, ls1 = 0.f;

  const ushort_t* Kb = Kf + (size_t)b * 32 * TILE_E;
  const ushort_t* Vb = Vf + (size_t)b * 32 * TILE_E;

  // ping-pong preloaded kb0 frag sets (named scalars, rule #20)
  uint4 a0, a1, a2, a3, a4, a5, a6, a7;
  uint4 b0, b1, b2, b3, b4, b5, b6, b7;
  {
    const ushort_t* kt0 = Kb + (size_t)pr * TILE_E;  // tile for i=0 (safe even if myNt==0)
    LDK8(a0, a1, a2, a3, a4, a5, a6, a7, kt0, 0);
  }
  int i = 0;
  while (i < myNt) {
    TILE_BODY(a0, a1, a2, a3, a4, a5, a6, a7, b0, b1, b2, b3, b4, b5, b6, b7, i);
    ++i;
    if (i >= myNt) break;
    TILE_BODY(b0, b1, b2, b3, b4, b5, b6, b7, a0, a1, a2, a3, a4, a5, a6, a7, i);
    ++i;
  }

  // ---- merge parities (pure adds; fixed-shift softmax) + normalize + store ----
  const float lsw = ls0 + ls1;
  const float rsw = lsw + __shfl_xor(lsw, 32);
  if (pr == 1) {
#pragma unroll
    for (int nb = 0; nb < 4; ++nb)
#pragma unroll
      for (int r = 0; r < 16; ++r)
        mO[wq][(nb * 16 + r) * 64 + lane] = o[nb][r];
    if (hi == 0) sRS[wq][l32] = rsw;
  }
  __syncthreads();
  if (pr == 0) {
    const float rs = rsw + sRS[wq][l32];
#pragma unroll
    for (int nb = 0; nb < 4; ++nb)
#pragma unroll
      for (int r = 0; r < 16; ++r) o[nb][r] += mO[wq][(nb * 16 + r) * 64 + lane];
    const float inv_own = 1.0f / rs;
#pragma unroll
    for (int r = 0; r < 16; ++r) {
      const int crow = (r & 3) + 8 * (r >> 2) + 4 * hi;
      const float inv = __shfl(inv_own, crow);
      float* op = Out + ((size_t)(b * NQ + q0 + wq * 32 + crow)) * DH + l32;
#pragma unroll
      for (int nb = 0; nb < 4; ++nb) op[nb * 32] = o[nb][r] * inv;
    }
  }
}

extern "C" void kernel_launch(void* const* d_in, const int* in_sizes, int n_in,
                              void* d_out, int out_size, void* d_ws, size_t ws_size,
                              hipStream_t stream) {
  const float* Q = (const float*)d_in[0];
  const float* K = (const float*)d_in[1];
  const float* V = (const float*)d_in[2];
  const int* vsl = (const int*)d_in[3];
  float* Out = (float*)d_out;

  // ws: Kf 16.78 MB + Vf 16.78 MB
  ushort_t* Kf = (ushort_t*)d_ws;
  ushort_t* Vf = Kf + (size_t)B_SZ * 32 * TILE_E;

  prep_kv<<<dim3(NK / 64, B_SZ), dim3(256), 0, stream>>>(K, V, Kf, Vf);
  attn<<<dim3(1024), dim3(256), 0, stream>>>(Q, Kf, Vf, vsl, Out);
}